// Round 2
// baseline (377.898 us; speedup 1.0000x reference)
//
#include <hip/hip_runtime.h>
#include <hip/hip_bf16.h>
#include <stdint.h>

// B=1, S=4096, D=1024, H=16, HD=64. I/O = float32; internal compute bf16 MFMA.
constexpr int SEQ  = 4096;
constexpr int DIM  = 1024;
constexpr int NH   = 16;
constexpr int HDM  = 64;

typedef __bf16 bf16;
typedef __attribute__((ext_vector_type(4))) float  f32x4;
typedef __attribute__((ext_vector_type(8))) __bf16 bf16x8;

__device__ __forceinline__ void gload_lds16(const bf16* g, bf16* l) {
  __builtin_amdgcn_global_load_lds(
      (const __attribute__((address_space(1))) unsigned int*)g,
      (__attribute__((address_space(3))) unsigned int*)l, 16, 0, 0);
}

// f32 -> bf16 for x + the 4 weight matrices. blockIdx.y selects tensor.
__global__ void cvt5(const float* __restrict__ x,  const float* __restrict__ wq,
                     const float* __restrict__ wk, const float* __restrict__ wv,
                     const float* __restrict__ wo,
                     bf16* __restrict__ xb,  bf16* __restrict__ wqb,
                     bf16* __restrict__ wkb, bf16* __restrict__ wvb,
                     bf16* __restrict__ wob) {
  const float* in; bf16* out; int n;
  switch (blockIdx.y) {
    case 0:  in = x;  out = xb;  n = SEQ * DIM; break;
    case 1:  in = wq; out = wqb; n = DIM * DIM; break;
    case 2:  in = wk; out = wkb; n = DIM * DIM; break;
    case 3:  in = wv; out = wvb; n = DIM * DIM; break;
    default: in = wo; out = wob; n = DIM * DIM; break;
  }
  const int i = (blockIdx.x * blockDim.x + threadIdx.x) * 8;
  if (i >= n) return;
  f32x4 a = *(const f32x4*)(in + i);
  f32x4 b = *(const f32x4*)(in + i + 4);
  bf16x8 o;
#pragma unroll
  for (int j = 0; j < 4; ++j) { o[j] = (bf16)a[j]; o[j + 4] = (bf16)b[j]; }
  *(bf16x8*)(out + i) = o;
}

// C[rows][1024] = A[rows][1024] * W[1024][1024]^T   (Linear: x @ W.T)
// 128x128 tile, BK=32, 4 waves each computing a 64x64 quadrant (4x4 MFMA frags).
template <typename OutT>
__global__ __launch_bounds__(256, 2)
void gemm_xwt(const bf16* __restrict__ A, const bf16* __restrict__ W,
              OutT* __restrict__ C) {
  __shared__ bf16 As[128 * 32];
  __shared__ bf16 Bs[128 * 32];
  const int tid = threadIdx.x;
  const int w   = tid >> 6;
  const int l   = tid & 63;
  const int l15 = l & 15, lhi = l >> 4;
  const int wr  = w >> 1, wc = w & 1;
  const int row0 = blockIdx.y * 128;
  const int col0 = blockIdx.x * 128;

  f32x4 acc[4][4] = {};

  const int srow = w * 32 + (l >> 2);
  const int scol = (l & 3) * 8;
  const bf16* gA = A + (size_t)(row0 + srow) * DIM + scol;
  const bf16* gB = W + (size_t)(col0 + srow) * DIM + scol;
  bf16* lA = As + srow * 32 + scol;
  bf16* lB = Bs + srow * 32 + scol;

  for (int k0 = 0; k0 < DIM; k0 += 32) {
    __syncthreads();
    gload_lds16(gA + k0,            lA);
    gload_lds16(gA + k0 + 16 * DIM, lA + 16 * 32);
    gload_lds16(gB + k0,            lB);
    gload_lds16(gB + k0 + 16 * DIM, lB + 16 * 32);
    __syncthreads();
    bf16x8 af[4], bf_[4];
#pragma unroll
    for (int m = 0; m < 4; ++m)
      af[m] = *(const bf16x8*)(As + (wr * 64 + m * 16 + l15) * 32 + lhi * 8);
#pragma unroll
    for (int n = 0; n < 4; ++n)
      bf_[n] = *(const bf16x8*)(Bs + (wc * 64 + n * 16 + l15) * 32 + lhi * 8);
#pragma unroll
    for (int m = 0; m < 4; ++m)
#pragma unroll
      for (int n = 0; n < 4; ++n)
        acc[m][n] = __builtin_amdgcn_mfma_f32_16x16x32_bf16(af[m], bf_[n], acc[m][n], 0, 0, 0);
  }

#pragma unroll
  for (int m = 0; m < 4; ++m)
#pragma unroll
    for (int n = 0; n < 4; ++n)
#pragma unroll
      for (int r = 0; r < 4; ++r) {
        const int row = row0 + wr * 64 + m * 16 + lhi * 4 + r;
        const int col = col0 + wc * 64 + n * 16 + l15;
        C[(size_t)row * DIM + col] = (OutT)acc[m][n][r];
      }
}

// Causal flash attention. block = (q-tile of 64 rows, head). 4 waves x 16 q-rows.
__global__ __launch_bounds__(256, 2)
void attn_fwd(const bf16* __restrict__ Qg, const bf16* __restrict__ Kg,
              const bf16* __restrict__ Vg, bf16* __restrict__ Og) {
  __shared__ bf16 Ps[64 * 72];  // P[q][k], +8 pad
  __shared__ bf16 Vt[64 * 72];  // Vt[d][k] = V[kv0+k][hc+d]
  const int tid = threadIdx.x;
  const int w   = tid >> 6;
  const int l   = tid & 63;
  const int l15 = l & 15, lhi = l >> 4;
  const int h  = blockIdx.y;
  const int qt = blockIdx.x;
  const int q0 = qt * 64;
  const int hc = h * HDM;

  bf16x8 aq[2];
#pragma unroll
  for (int ks = 0; ks < 2; ++ks)
    aq[ks] = *(const bf16x8*)(Qg + (size_t)(q0 + w * 16 + l15) * DIM + hc + ks * 32 + lhi * 8);

  f32x4 o_[4] = {};
  float m_[4], sum_[4];
#pragma unroll
  for (int r = 0; r < 4; ++r) { m_[r] = -3.0e38f; sum_[r] = 0.f; }

  const int vr  = tid >> 2;
  const int vc0 = (tid & 3) * 16;

  for (int t = 0; t <= qt; ++t) {
    const int kv0 = t * 64;
    __syncthreads();
    {
      const bf16* vsrc = Vg + (size_t)(kv0 + vr) * DIM + hc + vc0;
      bf16 vv[16];
      *(bf16x8*)(vv)     = *(const bf16x8*)(vsrc);
      *(bf16x8*)(vv + 8) = *(const bf16x8*)(vsrc + 8);
#pragma unroll
      for (int j = 0; j < 16; ++j) Vt[(vc0 + j) * 72 + vr] = vv[j];
    }
    f32x4 s[4] = {};
#pragma unroll
    for (int nt = 0; nt < 4; ++nt)
#pragma unroll
      for (int ks = 0; ks < 2; ++ks) {
        bf16x8 bk = *(const bf16x8*)(Kg + (size_t)(kv0 + nt * 16 + l15) * DIM + hc + ks * 32 + lhi * 8);
        s[nt] = __builtin_amdgcn_mfma_f32_16x16x32_bf16(aq[ks], bk, s[nt], 0, 0, 0);
      }
    const bool diag = (t == qt);
#pragma unroll
    for (int nt = 0; nt < 4; ++nt)
#pragma unroll
      for (int r = 0; r < 4; ++r) {
        float v = s[nt][r] * 0.125f;
        if (diag) {
          const int qq = w * 16 + lhi * 4 + r;
          const int kk = nt * 16 + l15;
          if (kk > qq) v = -1.0e30f;
        }
        s[nt][r] = v;
      }
    float pm[4], rs[4];
#pragma unroll
    for (int r = 0; r < 4; ++r) {
      pm[r] = fmaxf(fmaxf(s[0][r], s[1][r]), fmaxf(s[2][r], s[3][r]));
#pragma unroll
      for (int d = 1; d < 16; d <<= 1) pm[r] = fmaxf(pm[r], __shfl_xor(pm[r], d));
      const float mn = fmaxf(m_[r], pm[r]);
      const float al = __expf(m_[r] - mn);
      m_[r] = mn;
      sum_[r] *= al;
      o_[0][r] *= al; o_[1][r] *= al; o_[2][r] *= al; o_[3][r] *= al;
      rs[r] = 0.f;
    }
#pragma unroll
    for (int nt = 0; nt < 4; ++nt)
#pragma unroll
      for (int r = 0; r < 4; ++r) {
        const float p = __expf(s[nt][r] - m_[r]);
        s[nt][r] = p;
        rs[r] += p;
      }
#pragma unroll
    for (int r = 0; r < 4; ++r) {
#pragma unroll
      for (int d = 1; d < 16; d <<= 1) rs[r] += __shfl_xor(rs[r], d);
      sum_[r] += rs[r];
    }
#pragma unroll
    for (int nt = 0; nt < 4; ++nt)
#pragma unroll
      for (int r = 0; r < 4; ++r)
        Ps[(w * 16 + lhi * 4 + r) * 72 + nt * 16 + l15] = (bf16)s[nt][r];
    __syncthreads();
#pragma unroll
    for (int ks = 0; ks < 2; ++ks) {
      bf16x8 ap = *(const bf16x8*)(Ps + (w * 16 + l15) * 72 + ks * 32 + lhi * 8);
#pragma unroll
      for (int nt = 0; nt < 4; ++nt) {
        bf16x8 bv = *(const bf16x8*)(Vt + (nt * 16 + l15) * 72 + ks * 32 + lhi * 8);
        o_[nt] = __builtin_amdgcn_mfma_f32_16x16x32_bf16(ap, bv, o_[nt], 0, 0, 0);
      }
    }
  }
#pragma unroll
  for (int r = 0; r < 4; ++r) {
    const float inv = 1.0f / sum_[r];
#pragma unroll
    for (int nt = 0; nt < 4; ++nt)
      Og[(size_t)(q0 + w * 16 + lhi * 4 + r) * DIM + hc + nt * 16 + l15] =
          (bf16)(o_[nt][r] * inv);
  }
}

extern "C" void kernel_launch(void* const* d_in, const int* in_sizes, int n_in,
                              void* d_out, int out_size, void* d_ws, size_t ws_size,
                              hipStream_t stream) {
  const float* x  = (const float*)d_in[0];
  const float* Wq = (const float*)d_in[1];
  const float* Wk = (const float*)d_in[2];
  const float* Wv = (const float*)d_in[3];
  const float* Wo = (const float*)d_in[4];
  float* out = (float*)d_out;

  // ws layout (bf16): x 8MB | Wq..Wo 2MB each | Q,K,V,At 8MB each  => 48MB
  bf16* xb  = (bf16*)d_ws;
  bf16* wqb = xb  + (size_t)SEQ * DIM;
  bf16* wkb = wqb + (size_t)DIM * DIM;
  bf16* wvb = wkb + (size_t)DIM * DIM;
  bf16* wob = wvb + (size_t)DIM * DIM;
  bf16* Qs  = wob + (size_t)DIM * DIM;
  bf16* Ks  = Qs  + (size_t)SEQ * DIM;
  bf16* Vs  = Ks  + (size_t)SEQ * DIM;
  bf16* At  = Vs  + (size_t)SEQ * DIM;

  cvt5<<<dim3((SEQ * DIM) / (256 * 8), 5), 256, 0, stream>>>(
      x, Wq, Wk, Wv, Wo, xb, wqb, wkb, wvb, wob);

  dim3 gg(DIM / 128, SEQ / 128);
  gemm_xwt<bf16><<<gg, 256, 0, stream>>>(xb, wqb, Qs);
  gemm_xwt<bf16><<<gg, 256, 0, stream>>>(xb, wkb, Ks);
  gemm_xwt<bf16><<<gg, 256, 0, stream>>>(xb, wvb, Vs);
  attn_fwd<<<dim3(SEQ / 64, NH), 256, 0, stream>>>(Qs, Ks, Vs, At);
  gemm_xwt<float><<<gg, 256, 0, stream>>>(At, wob, out);
}

// Round 3
// 317.350 us; speedup vs baseline: 1.1908x; 1.1908x over previous
//
#include <hip/hip_runtime.h>
#include <hip/hip_bf16.h>
#include <stdint.h>

// B=1, S=4096, D=1024, H=16, HD=64. I/O = float32; internal compute bf16 MFMA.
constexpr int SEQ  = 4096;
constexpr int DIM  = 1024;
constexpr int NH   = 16;
constexpr int HDM  = 64;

typedef __bf16 bf16;
typedef __attribute__((ext_vector_type(4))) float  f32x4;
typedef __attribute__((ext_vector_type(8))) __bf16 bf16x8;

__device__ __forceinline__ void gload_lds16(const bf16* g, bf16* l) {
  __builtin_amdgcn_global_load_lds(
      (const __attribute__((address_space(1))) unsigned int*)g,
      (__attribute__((address_space(3))) unsigned int*)l, 16, 0, 0);
}

// f32 -> bf16 for x + the 4 weight matrices. blockIdx.y selects tensor.
__global__ void cvt5(const float* __restrict__ x,  const float* __restrict__ wq,
                     const float* __restrict__ wk, const float* __restrict__ wv,
                     const float* __restrict__ wo,
                     bf16* __restrict__ xb,  bf16* __restrict__ wqb,
                     bf16* __restrict__ wkb, bf16* __restrict__ wvb,
                     bf16* __restrict__ wob) {
  const float* in; bf16* out; int n;
  switch (blockIdx.y) {
    case 0:  in = x;  out = xb;  n = SEQ * DIM; break;
    case 1:  in = wq; out = wqb; n = DIM * DIM; break;
    case 2:  in = wk; out = wkb; n = DIM * DIM; break;
    case 3:  in = wv; out = wvb; n = DIM * DIM; break;
    default: in = wo; out = wob; n = DIM * DIM; break;
  }
  const int i = (blockIdx.x * blockDim.x + threadIdx.x) * 8;
  if (i >= n) return;
  f32x4 a = *(const f32x4*)(in + i);
  f32x4 b = *(const f32x4*)(in + i + 4);
  bf16x8 o;
#pragma unroll
  for (int j = 0; j < 4; ++j) { o[j] = (bf16)a[j]; o[j + 4] = (bf16)b[j]; }
  *(bf16x8*)(out + i) = o;
}

// ---------------- GEMM: C = A[rows][1024] * W[1024][1024]^T ----------------
// 128x128 tile, BK=32, 4 waves each a 64x64 quadrant. QKV=true: z picks W/out.
template <typename OutT, bool QKV>
__global__ __launch_bounds__(256, 2)
void gemm_xwt(const bf16* __restrict__ A,
              const bf16* __restrict__ W0, const bf16* __restrict__ W1,
              const bf16* __restrict__ W2,
              OutT* __restrict__ C0, OutT* __restrict__ C1, OutT* __restrict__ C2) {
  const bf16* W;
  OutT* C;
  if (QKV) {
    const int z = blockIdx.z;
    W = (z == 0) ? W0 : (z == 1) ? W1 : W2;
    C = (z == 0) ? C0 : (z == 1) ? C1 : C2;
  } else {
    W = W0; C = C0;
  }
  __shared__ bf16 As[128 * 32];
  __shared__ bf16 Bs[128 * 32];
  const int tid = threadIdx.x;
  const int w   = tid >> 6;
  const int l   = tid & 63;
  const int l15 = l & 15, lhi = l >> 4;
  const int wr  = w >> 1, wc = w & 1;
  const int row0 = blockIdx.y * 128;
  const int col0 = blockIdx.x * 128;

  f32x4 acc[4][4] = {};

  const int srow = w * 32 + (l >> 2);
  const int scol = (l & 3) * 8;
  const bf16* gA = A + (size_t)(row0 + srow) * DIM + scol;
  const bf16* gB = W + (size_t)(col0 + srow) * DIM + scol;
  bf16* lA = As + srow * 32 + scol;
  bf16* lB = Bs + srow * 32 + scol;

  for (int k0 = 0; k0 < DIM; k0 += 32) {
    __syncthreads();
    gload_lds16(gA + k0,            lA);
    gload_lds16(gA + k0 + 16 * DIM, lA + 16 * 32);
    gload_lds16(gB + k0,            lB);
    gload_lds16(gB + k0 + 16 * DIM, lB + 16 * 32);
    __syncthreads();
    bf16x8 af[4], bf_[4];
#pragma unroll
    for (int m = 0; m < 4; ++m)
      af[m] = *(const bf16x8*)(As + (wr * 64 + m * 16 + l15) * 32 + lhi * 8);
#pragma unroll
    for (int n = 0; n < 4; ++n)
      bf_[n] = *(const bf16x8*)(Bs + (wc * 64 + n * 16 + l15) * 32 + lhi * 8);
#pragma unroll
    for (int m = 0; m < 4; ++m)
#pragma unroll
      for (int n = 0; n < 4; ++n)
        acc[m][n] = __builtin_amdgcn_mfma_f32_16x16x32_bf16(af[m], bf_[n], acc[m][n], 0, 0, 0);
  }

#pragma unroll
  for (int m = 0; m < 4; ++m)
#pragma unroll
    for (int n = 0; n < 4; ++n)
#pragma unroll
      for (int r = 0; r < 4; ++r) {
        const int row = row0 + wr * 64 + m * 16 + lhi * 4 + r;
        const int col = col0 + wc * 64 + n * 16 + l15;
        C[(size_t)row * DIM + col] = (OutT)acc[m][n][r];
      }
}

// --------------- V transpose: Vt[d][s] = Vs[s][d]  (once) -------------------
__global__ __launch_bounds__(256)
void transpose_v(const bf16* __restrict__ Vs, bf16* __restrict__ Vt) {
  __shared__ bf16 t[64][72];
  const int st = blockIdx.x * 64;
  const int dt = blockIdx.y * 64;
  const int tid = threadIdx.x;
  const int r  = tid >> 2;
  const int c0 = (tid & 3) * 16;
  bf16x8 a = *(const bf16x8*)(Vs + (size_t)(st + r) * DIM + dt + c0);
  bf16x8 b = *(const bf16x8*)(Vs + (size_t)(st + r) * DIM + dt + c0 + 8);
#pragma unroll
  for (int j = 0; j < 8; ++j) { t[r][c0 + j] = a[j]; t[r][c0 + 8 + j] = b[j]; }
  __syncthreads();
  const int d  = tid >> 2;
  const int s0 = (tid & 3) * 16;
  bf16x8 o1, o2;
#pragma unroll
  for (int j = 0; j < 8; ++j) { o1[j] = t[s0 + j][d]; o2[j] = t[s0 + 8 + j][d]; }
  bf16* dst = Vt + (size_t)(dt + d) * SEQ + st + s0;
  *(bf16x8*)(dst)     = o1;
  *(bf16x8*)(dst + 8) = o2;
}

// --------------- Causal flash attention: 1 wave / block ---------------------
// q-tile = 16 rows. Block handles pair (i, 255-i): exactly 65 KV iterations.
// K b-frags and V^T b-frags straight from global (L2-hot). No barriers.
__global__ __launch_bounds__(64, 4)
void attn_fwd(const bf16* __restrict__ Qg, const bf16* __restrict__ Kg,
              const bf16* __restrict__ Vt, bf16* __restrict__ Og) {
  __shared__ bf16 Ps[16 * 72];  // wave-private P bounce (D-layout -> A-frag)
  const int l   = threadIdx.x & 63;
  const int l15 = l & 15, lhi = l >> 4;
  const int p  = blockIdx.x >> 4;   // pair index 0..127
  const int h  = blockIdx.x & 15;
  const int hc = h * HDM;

#pragma unroll 1
  for (int half = 0; half < 2; ++half) {
    const int i  = half ? (255 - p) : p;   // 16-row q-tile index
    const int q0 = i * 16;
    const int tlast = i >> 2;              // last 64-wide KV tile
    const int qloc = (i & 3) * 16;         // q offset inside last KV tile

    bf16x8 aq[2];
#pragma unroll
    for (int ks = 0; ks < 2; ++ks)
      aq[ks] = *(const bf16x8*)(Qg + (size_t)(q0 + l15) * DIM + hc + ks * 32 + lhi * 8);

    f32x4 o_[4] = {};
    float m_[4], sum_[4];
#pragma unroll
    for (int r = 0; r < 4; ++r) { m_[r] = -3.0e38f; sum_[r] = 0.f; }

#pragma unroll 1
    for (int t = 0; t <= tlast; ++t) {
      const int kv0 = t * 64;
      // QK^T
      bf16x8 kf[4][2];
#pragma unroll
      for (int nt = 0; nt < 4; ++nt)
#pragma unroll
        for (int ks = 0; ks < 2; ++ks)
          kf[nt][ks] = *(const bf16x8*)(Kg + (size_t)(kv0 + nt * 16 + l15) * DIM + hc + ks * 32 + lhi * 8);
      f32x4 s[4] = {};
#pragma unroll
      for (int nt = 0; nt < 4; ++nt)
#pragma unroll
        for (int ks = 0; ks < 2; ++ks)
          s[nt] = __builtin_amdgcn_mfma_f32_16x16x32_bf16(aq[ks], kf[nt][ks], s[nt], 0, 0, 0);
      // V^T frags (issue early; latency hides under softmax)
      bf16x8 vf[4][2];
#pragma unroll
      for (int nt = 0; nt < 4; ++nt)
#pragma unroll
        for (int ks = 0; ks < 2; ++ks)
          vf[nt][ks] = *(const bf16x8*)(Vt + (size_t)(hc + nt * 16 + l15) * SEQ + kv0 + ks * 32 + lhi * 8);
      // scale + causal mask
      const bool diag = (t == tlast);
#pragma unroll
      for (int nt = 0; nt < 4; ++nt)
#pragma unroll
        for (int r = 0; r < 4; ++r) {
          float v = s[nt][r] * 0.125f;
          if (diag && (nt * 16 + l15 > qloc + lhi * 4 + r)) v = -1.0e30f;
          s[nt][r] = v;
        }
      // online softmax (row spread over 16 lanes l15, 4 nt-tiles)
      float pm[4], rs[4];
#pragma unroll
      for (int r = 0; r < 4; ++r) {
        pm[r] = fmaxf(fmaxf(s[0][r], s[1][r]), fmaxf(s[2][r], s[3][r]));
#pragma unroll
        for (int d = 1; d < 16; d <<= 1) pm[r] = fmaxf(pm[r], __shfl_xor(pm[r], d));
        const float mn = fmaxf(m_[r], pm[r]);
        const float al = __expf(m_[r] - mn);
        m_[r] = mn;
        sum_[r] *= al;
        o_[0][r] *= al; o_[1][r] *= al; o_[2][r] *= al; o_[3][r] *= al;
        rs[r] = 0.f;
      }
#pragma unroll
      for (int nt = 0; nt < 4; ++nt)
#pragma unroll
        for (int r = 0; r < 4; ++r) {
          const float pv = __expf(s[nt][r] - m_[r]);
          s[nt][r] = pv;
          rs[r] += pv;
        }
#pragma unroll
      for (int r = 0; r < 4; ++r) {
#pragma unroll
        for (int d = 1; d < 16; d <<= 1) rs[r] += __shfl_xor(rs[r], d);
        sum_[r] += rs[r];
      }
      // P -> LDS (wave-private; DS ops in-order per wave, no barrier needed)
#pragma unroll
      for (int nt = 0; nt < 4; ++nt)
#pragma unroll
        for (int r = 0; r < 4; ++r)
          Ps[(lhi * 4 + r) * 72 + nt * 16 + l15] = (bf16)s[nt][r];
      // O += P V
#pragma unroll
      for (int ks = 0; ks < 2; ++ks) {
        bf16x8 ap = *(const bf16x8*)(Ps + l15 * 72 + ks * 32 + lhi * 8);
#pragma unroll
        for (int nt = 0; nt < 4; ++nt)
          o_[nt] = __builtin_amdgcn_mfma_f32_16x16x32_bf16(ap, vf[nt][ks], o_[nt], 0, 0, 0);
      }
    }
#pragma unroll
    for (int r = 0; r < 4; ++r) {
      const float inv = 1.0f / sum_[r];
#pragma unroll
      for (int nt = 0; nt < 4; ++nt)
        Og[(size_t)(q0 + lhi * 4 + r) * DIM + hc + nt * 16 + l15] =
            (bf16)(o_[nt][r] * inv);
    }
  }
}

extern "C" void kernel_launch(void* const* d_in, const int* in_sizes, int n_in,
                              void* d_out, int out_size, void* d_ws, size_t ws_size,
                              hipStream_t stream) {
  const float* x  = (const float*)d_in[0];
  const float* Wq = (const float*)d_in[1];
  const float* Wk = (const float*)d_in[2];
  const float* Wv = (const float*)d_in[3];
  const float* Wo = (const float*)d_in[4];
  float* out = (float*)d_out;

  // ws (bf16, 48MB): xb 8MB | Wq..Wo 2MB each | Q,K,V 8MB each
  // aliases: Vt <- xb (xb dead after QKV gemm); At <- Vs (Vs dead after transpose)
  bf16* xb  = (bf16*)d_ws;
  bf16* wqb = xb  + (size_t)SEQ * DIM;
  bf16* wkb = wqb + (size_t)DIM * DIM;
  bf16* wvb = wkb + (size_t)DIM * DIM;
  bf16* wob = wvb + (size_t)DIM * DIM;
  bf16* Qs  = wob + (size_t)DIM * DIM;
  bf16* Ks  = Qs  + (size_t)SEQ * DIM;
  bf16* Vs  = Ks  + (size_t)SEQ * DIM;
  bf16* Vt  = xb;   // [DIM][SEQ]
  bf16* At  = Vs;

  cvt5<<<dim3((SEQ * DIM) / (256 * 8), 5), 256, 0, stream>>>(
      x, Wq, Wk, Wv, Wo, xb, wqb, wkb, wvb, wob);

  gemm_xwt<bf16, true><<<dim3(DIM / 128, SEQ / 128, 3), 256, 0, stream>>>(
      xb, wqb, wkb, wvb, Qs, Ks, Vs);

  transpose_v<<<dim3(SEQ / 64, DIM / 64), 256, 0, stream>>>(Vs, Vt);

  attn_fwd<<<dim3(128 * NH), 64, 0, stream>>>(Qs, Ks, Vt, At);

  gemm_xwt<float, false><<<dim3(DIM / 128, SEQ / 128), 256, 0, stream>>>(
      At, wob, nullptr, nullptr, out, nullptr, nullptr);
}

// Round 4
// 225.045 us; speedup vs baseline: 1.6792x; 1.4102x over previous
//
#include <hip/hip_runtime.h>
#include <hip/hip_bf16.h>
#include <stdint.h>

// B=1, S=4096, D=1024, H=16, HD=64. I/O = float32; internal compute bf16 MFMA.
constexpr int SEQ  = 4096;
constexpr int DIM  = 1024;
constexpr int NH   = 16;
constexpr int HDM  = 64;

typedef __bf16 bf16;
typedef __attribute__((ext_vector_type(4)))  float  f32x4;
typedef __attribute__((ext_vector_type(16))) float  f32x16;
typedef __attribute__((ext_vector_type(8)))  __bf16 bf16x8;
typedef __attribute__((ext_vector_type(4)))  __bf16 bf16x4;
typedef __attribute__((ext_vector_type(4)))  unsigned u32x4;

__device__ __forceinline__ void gload_lds16(const bf16* g, bf16* l) {
  __builtin_amdgcn_global_load_lds(
      (const __attribute__((address_space(1))) unsigned int*)g,
      (__attribute__((address_space(3))) unsigned int*)l, 16, 0, 0);
}

__device__ __forceinline__ unsigned pack2(float lo, float hi) {
  unsigned short a = __builtin_bit_cast(unsigned short, (bf16)lo);
  unsigned short b = __builtin_bit_cast(unsigned short, (bf16)hi);
  return ((unsigned)b << 16) | a;
}

// f32 -> bf16 for x + the 4 weight matrices. blockIdx.y selects tensor.
__global__ void cvt5(const float* __restrict__ x,  const float* __restrict__ wq,
                     const float* __restrict__ wk, const float* __restrict__ wv,
                     const float* __restrict__ wo,
                     bf16* __restrict__ xb,  bf16* __restrict__ wqb,
                     bf16* __restrict__ wkb, bf16* __restrict__ wvb,
                     bf16* __restrict__ wob) {
  const float* in; bf16* out; int n;
  switch (blockIdx.y) {
    case 0:  in = x;  out = xb;  n = SEQ * DIM; break;
    case 1:  in = wq; out = wqb; n = DIM * DIM; break;
    case 2:  in = wk; out = wkb; n = DIM * DIM; break;
    case 3:  in = wv; out = wvb; n = DIM * DIM; break;
    default: in = wo; out = wob; n = DIM * DIM; break;
  }
  const int i = (blockIdx.x * blockDim.x + threadIdx.x) * 8;
  if (i >= n) return;
  f32x4 a = *(const f32x4*)(in + i);
  f32x4 b = *(const f32x4*)(in + i + 4);
  bf16x8 o;
#pragma unroll
  for (int j = 0; j < 4; ++j) { o[j] = (bf16)a[j]; o[j + 4] = (bf16)b[j]; }
  *(bf16x8*)(out + i) = o;
}

// ---------------- GEMM: C = A[rows][1024] * W[1024][1024]^T ----------------
template <typename OutT, bool QKV>
__global__ __launch_bounds__(256, 2)
void gemm_xwt(const bf16* __restrict__ A,
              const bf16* __restrict__ W0, const bf16* __restrict__ W1,
              const bf16* __restrict__ W2,
              OutT* __restrict__ C0, OutT* __restrict__ C1, OutT* __restrict__ C2) {
  const bf16* W;
  OutT* C;
  if (QKV) {
    const int z = blockIdx.z;
    W = (z == 0) ? W0 : (z == 1) ? W1 : W2;
    C = (z == 0) ? C0 : (z == 1) ? C1 : C2;
  } else {
    W = W0; C = C0;
  }
  __shared__ bf16 As[128 * 32];
  __shared__ bf16 Bs[128 * 32];
  const int tid = threadIdx.x;
  const int w   = tid >> 6;
  const int l   = tid & 63;
  const int l15 = l & 15, lhi = l >> 4;
  const int wr  = w >> 1, wc = w & 1;
  const int row0 = blockIdx.y * 128;
  const int col0 = blockIdx.x * 128;

  f32x4 acc[4][4] = {};

  const int srow = w * 32 + (l >> 2);
  const int scol = (l & 3) * 8;
  const bf16* gA = A + (size_t)(row0 + srow) * DIM + scol;
  const bf16* gB = W + (size_t)(col0 + srow) * DIM + scol;
  bf16* lA = As + srow * 32 + scol;
  bf16* lB = Bs + srow * 32 + scol;

  for (int k0 = 0; k0 < DIM; k0 += 32) {
    __syncthreads();
    gload_lds16(gA + k0,            lA);
    gload_lds16(gA + k0 + 16 * DIM, lA + 16 * 32);
    gload_lds16(gB + k0,            lB);
    gload_lds16(gB + k0 + 16 * DIM, lB + 16 * 32);
    __syncthreads();
    bf16x8 af[4], bf_[4];
#pragma unroll
    for (int m = 0; m < 4; ++m)
      af[m] = *(const bf16x8*)(As + (wr * 64 + m * 16 + l15) * 32 + lhi * 8);
#pragma unroll
    for (int n = 0; n < 4; ++n)
      bf_[n] = *(const bf16x8*)(Bs + (wc * 64 + n * 16 + l15) * 32 + lhi * 8);
#pragma unroll
    for (int m = 0; m < 4; ++m)
#pragma unroll
      for (int n = 0; n < 4; ++n)
        acc[m][n] = __builtin_amdgcn_mfma_f32_16x16x32_bf16(af[m], bf_[n], acc[m][n], 0, 0, 0);
  }

#pragma unroll
  for (int m = 0; m < 4; ++m)
#pragma unroll
    for (int n = 0; n < 4; ++n)
#pragma unroll
      for (int r = 0; r < 4; ++r) {
        const int row = row0 + wr * 64 + m * 16 + lhi * 4 + r;
        const int col = col0 + wc * 64 + n * 16 + l15;
        C[(size_t)row * DIM + col] = (OutT)acc[m][n][r];
      }
}

// --------------- V transpose: Vt[d][s] = Vs[s][d]  (once) -------------------
__global__ __launch_bounds__(256)
void transpose_v(const bf16* __restrict__ Vs, bf16* __restrict__ Vt) {
  __shared__ bf16 t[64][72];
  const int st = blockIdx.x * 64;
  const int dt = blockIdx.y * 64;
  const int tid = threadIdx.x;
  const int r  = tid >> 2;
  const int c0 = (tid & 3) * 16;
  bf16x8 a = *(const bf16x8*)(Vs + (size_t)(st + r) * DIM + dt + c0);
  bf16x8 b = *(const bf16x8*)(Vs + (size_t)(st + r) * DIM + dt + c0 + 8);
#pragma unroll
  for (int j = 0; j < 8; ++j) { t[r][c0 + j] = a[j]; t[r][c0 + 8 + j] = b[j]; }
  __syncthreads();
  const int d  = tid >> 2;
  const int s0 = (tid & 3) * 16;
  bf16x8 o1, o2;
#pragma unroll
  for (int j = 0; j < 8; ++j) { o1[j] = t[s0 + j][d]; o2[j] = t[s0 + 8 + j][d]; }
  bf16* dst = Vt + (size_t)(dt + d) * SEQ + st + s0;
  *(bf16x8*)(dst)     = o1;
  *(bf16x8*)(dst + 8) = o2;
}

// --------------- Causal flash attention, swapped-operand 32x32 --------------
// 1 wave/block; wave owns 32 q-rows. S^T = K Q^T (lane = one q-col, k in regs),
// O^T = V^T P^T (same q-per-lane layout). Softmax is lane-local except one
// max-exchange shuffle; sum reduced once at epilogue. No LDS, no barriers.
__global__ __launch_bounds__(64, 2)
void attn_fwd(const bf16* __restrict__ Qg, const bf16* __restrict__ Kg,
              const bf16* __restrict__ Vt, bf16* __restrict__ Og) {
  const int l   = threadIdx.x;
  const int l31 = l & 31;
  const int hi  = l >> 5;
  const int h   = blockIdx.x & 15;
  const int i   = 127 - (int)(blockIdx.x >> 4);  // big tiles dispatch first
  const int q0  = i * 32;
  const int hc  = h * HDM;
  const int tlast = i >> 1;
  const int qg  = q0 + l31;
  constexpr float C = 0.18033688011112042f;  // 0.125 * log2(e)

  // Q B-frags (kept in regs): lane holds Q[q0+l31][hc + ks*16 + hi*8 ..+8)
  bf16x8 qf[4];
#pragma unroll
  for (int ks = 0; ks < 4; ++ks)
    qf[ks] = *(const bf16x8*)(Qg + (size_t)qg * DIM + hc + ks * 16 + hi * 8);

  f32x16 ot0 = {}, ot1 = {};          // O^T: d = nt*32 + (r&3)+8*(r>>2)+4*hi
  float m2 = -3.0e38f, sum_ = 0.f;    // scaled-domain running max, partial sum

#pragma unroll 1
  for (int t = 0; t <= tlast; ++t) {
    const int kv0 = t * 64;
    // K A-frags: lane holds K[kv0+sub*32+l31][hc + ks*16 + hi*8 ..+8)
    bf16x8 kf0[4], kf1[4];
#pragma unroll
    for (int ks = 0; ks < 4; ++ks) {
      kf0[ks] = *(const bf16x8*)(Kg + (size_t)(kv0 + l31) * DIM + hc + ks * 16 + hi * 8);
      kf1[ks] = *(const bf16x8*)(Kg + (size_t)(kv0 + 32 + l31) * DIM + hc + ks * 16 + hi * 8);
    }
    f32x16 s0 = {}, s1 = {};
#pragma unroll
    for (int ks = 0; ks < 4; ++ks) {
      s0 = __builtin_amdgcn_mfma_f32_32x32x16_bf16(kf0[ks], qf[ks], s0, 0, 0, 0);
      s1 = __builtin_amdgcn_mfma_f32_32x32x16_bf16(kf1[ks], qf[ks], s1, 0, 0, 0);
    }
    // V^T A-frags (issued early; latency hides under softmax)
    bf16x8 vf0[4], vf1[4];
#pragma unroll
    for (int k2 = 0; k2 < 4; ++k2) {
      vf0[k2] = *(const bf16x8*)(Vt + (size_t)(hc + l31) * SEQ + kv0 + k2 * 16 + hi * 8);
      vf1[k2] = *(const bf16x8*)(Vt + (size_t)(hc + 32 + l31) * SEQ + kv0 + k2 * 16 + hi * 8);
    }
    // scale (+ causal mask on diagonal tile); s-reg r holds k = kv0+sub*32+kp
    if (t == tlast) {
#pragma unroll
      for (int r = 0; r < 16; ++r) {
        const int kp = (r & 3) + 8 * (r >> 2) + 4 * hi;
        s0[r] = (kv0 + kp      > qg) ? -1.0e30f : s0[r] * C;
        s1[r] = (kv0 + 32 + kp > qg) ? -1.0e30f : s1[r] * C;
      }
    } else {
#pragma unroll
      for (int r = 0; r < 16; ++r) { s0[r] *= C; s1[r] *= C; }
    }
    // row max: 31 in-lane + 1 partner exchange
    float pm = fmaxf(s0[0], s1[0]);
#pragma unroll
    for (int r = 1; r < 16; ++r) pm = fmaxf(pm, fmaxf(s0[r], s1[r]));
    pm = fmaxf(pm, __shfl_xor(pm, 32));
    const float mn = fmaxf(m2, pm);
    const float al = __builtin_exp2f(m2 - mn);
    m2 = mn;
    sum_ *= al;
#pragma unroll
    for (int r = 0; r < 16; ++r) { ot0[r] *= al; ot1[r] *= al; }
    // p = exp2(s - m2); lane-partial sum (reduced once at epilogue)
    float rs = 0.f;
#pragma unroll
    for (int r = 0; r < 16; ++r) {
      s0[r] = __builtin_exp2f(s0[r] - m2);
      s1[r] = __builtin_exp2f(s1[r] - m2);
      rs += s0[r] + s1[r];
    }
    sum_ += rs;
    // P^T B-frags: frag[k2] covers kk in [k2*16, k2*16+16).
    // lane needs kk = 8*hi + j; own regs give half, partner (l^32) the rest.
#pragma unroll
    for (int sub = 0; sub < 2; ++sub) {
#pragma unroll
      for (int hf = 0; hf < 2; ++hf) {
        const int rb = hf * 8;
        float v0, v1, v2, v3, v4, v5, v6, v7;
        if (sub == 0) {
          v0 = s0[rb+0]; v1 = s0[rb+1]; v2 = s0[rb+2]; v3 = s0[rb+3];
          v4 = s0[rb+4]; v5 = s0[rb+5]; v6 = s0[rb+6]; v7 = s0[rb+7];
        } else {
          v0 = s1[rb+0]; v1 = s1[rb+1]; v2 = s1[rb+2]; v3 = s1[rb+3];
          v4 = s1[rb+4]; v5 = s1[rb+5]; v6 = s1[rb+6]; v7 = s1[rb+7];
        }
        const unsigned w0 = pack2(v0, v1), w1 = pack2(v2, v3);
        const unsigned w2 = pack2(v4, v5), w3 = pack2(v6, v7);
        const unsigned y0 = __shfl_xor((int)w0, 32), y1 = __shfl_xor((int)w1, 32);
        const unsigned y2 = __shfl_xor((int)w2, 32), y3 = __shfl_xor((int)w3, 32);
        u32x4 fu;
        fu[0] = hi ? y2 : w0;  // kk 8hi+0,1
        fu[1] = hi ? y3 : w1;  // kk 8hi+2,3
        fu[2] = hi ? w2 : y0;  // kk 8hi+4,5
        fu[3] = hi ? w3 : y1;  // kk 8hi+6,7
        const bf16x8 pb = __builtin_bit_cast(bf16x8, fu);
        if (sub == 0 && hf == 0) { ot0 = __builtin_amdgcn_mfma_f32_32x32x16_bf16(vf0[0], pb, ot0, 0, 0, 0);
                                   ot1 = __builtin_amdgcn_mfma_f32_32x32x16_bf16(vf1[0], pb, ot1, 0, 0, 0); }
        if (sub == 0 && hf == 1) { ot0 = __builtin_amdgcn_mfma_f32_32x32x16_bf16(vf0[1], pb, ot0, 0, 0, 0);
                                   ot1 = __builtin_amdgcn_mfma_f32_32x32x16_bf16(vf1[1], pb, ot1, 0, 0, 0); }
        if (sub == 1 && hf == 0) { ot0 = __builtin_amdgcn_mfma_f32_32x32x16_bf16(vf0[2], pb, ot0, 0, 0, 0);
                                   ot1 = __builtin_amdgcn_mfma_f32_32x32x16_bf16(vf1[2], pb, ot1, 0, 0, 0); }
        if (sub == 1 && hf == 1) { ot0 = __builtin_amdgcn_mfma_f32_32x32x16_bf16(vf0[3], pb, ot0, 0, 0, 0);
                                   ot1 = __builtin_amdgcn_mfma_f32_32x32x16_bf16(vf1[3], pb, ot1, 0, 0, 0); }
      }
    }
  }
  // epilogue: one sum exchange, normalize, write O (row qg, d-runs of 4)
  sum_ += __shfl_xor(sum_, 32);
  const float inv = 1.0f / sum_;
#pragma unroll
  for (int g = 0; g < 4; ++g) {
    bf16x4 o0, o1;
#pragma unroll
    for (int e = 0; e < 4; ++e) {
      o0[e] = (bf16)(ot0[g * 4 + e] * inv);
      o1[e] = (bf16)(ot1[g * 4 + e] * inv);
    }
    *(bf16x4*)(Og + (size_t)qg * DIM + hc + g * 8 + hi * 4)      = o0;
    *(bf16x4*)(Og + (size_t)qg * DIM + hc + 32 + g * 8 + hi * 4) = o1;
  }
}

extern "C" void kernel_launch(void* const* d_in, const int* in_sizes, int n_in,
                              void* d_out, int out_size, void* d_ws, size_t ws_size,
                              hipStream_t stream) {
  const float* x  = (const float*)d_in[0];
  const float* Wq = (const float*)d_in[1];
  const float* Wk = (const float*)d_in[2];
  const float* Wv = (const float*)d_in[3];
  const float* Wo = (const float*)d_in[4];
  float* out = (float*)d_out;

  // ws (bf16, 48MB): xb 8MB | Wq..Wo 2MB each | Q,K,V 8MB each
  // aliases: Vt <- xb (xb dead after QKV gemm); At <- Vs (Vs dead after transpose)
  bf16* xb  = (bf16*)d_ws;
  bf16* wqb = xb  + (size_t)SEQ * DIM;
  bf16* wkb = wqb + (size_t)DIM * DIM;
  bf16* wvb = wkb + (size_t)DIM * DIM;
  bf16* wob = wvb + (size_t)DIM * DIM;
  bf16* Qs  = wob + (size_t)DIM * DIM;
  bf16* Ks  = Qs  + (size_t)SEQ * DIM;
  bf16* Vs  = Ks  + (size_t)SEQ * DIM;
  bf16* Vt  = xb;   // [DIM][SEQ]
  bf16* At  = Vs;

  cvt5<<<dim3((SEQ * DIM) / (256 * 8), 5), 256, 0, stream>>>(
      x, Wq, Wk, Wv, Wo, xb, wqb, wkb, wvb, wob);

  gemm_xwt<bf16, true><<<dim3(DIM / 128, SEQ / 128, 3), 256, 0, stream>>>(
      xb, wqb, wkb, wvb, Qs, Ks, Vs);

  transpose_v<<<dim3(SEQ / 64, DIM / 64), 256, 0, stream>>>(Vs, Vt);

  attn_fwd<<<dim3(128 * NH), 64, 0, stream>>>(Qs, Ks, Vt, At);

  gemm_xwt<float, false><<<dim3(DIM / 128, SEQ / 128), 256, 0, stream>>>(
      At, wob, nullptr, nullptr, out, nullptr, nullptr);
}